// Round 14
// baseline (639.410 us; speedup 1.0000x reference)
//
#include <hip/hip_runtime.h>
#include <cstdint>
#include <cstddef>

#define HID 128

using bf16x8 = __attribute__((ext_vector_type(8))) short;
using f32x4v = __attribute__((ext_vector_type(4))) float;

// ---------------- bf16 helpers (RNE) ----------------
static __device__ __forceinline__ unsigned short f2b(float x) {
  unsigned int u = __float_as_uint(x);
  unsigned int r = u + 0x7FFFu + ((u >> 16) & 1u);
  return (unsigned short)(r >> 16);
}
static __device__ __forceinline__ float b2f(unsigned short h) {
  return __uint_as_float(((unsigned int)h) << 16);
}

static __device__ __forceinline__ int lowerb(const int* __restrict__ a, int n, int v) {
  int lo = 0, hi = n;
  while (lo < hi) { int m = (lo + hi) >> 1; if (a[m] < v) lo = m + 1; else hi = m; }
  return lo;
}

// ---------------- prep1: XCD-partitioned hist(4seg) + wcvt + vx_init ----------------
__global__ __launch_bounds__(256)
void k_prep1(const int* p_dst, int EP, int* deg_p, const int* d_dst, int ED, int* deg_d,
             const int* p_si, int SP, int* scnt_p, const int* d_si, int SD, int* scnt_d,
             int NP, int ND,
             const float* convW_d, const float* convW_p,
             const float* enc_Wd, const float* enc_Wp,
             unsigned short* WhiAll, unsigned short* WloAll,
             const float* emb_d, const float* d_feat, float* vx_d,
             const float* emb_p, const float* p_feat, float* vx_p, int vhalf) {
  const int b = blockIdx.x;
  const int tid = threadIdx.x;
  if (b < 1024) {
    const int xcd = b & 7;
    const int rest = b >> 3;
    const int seg = rest & 3;
    const int lb = rest >> 2;
    const int stride = 32 * 256;
    const int* idx = seg == 0 ? p_dst : seg == 1 ? d_dst : seg == 2 ? p_si : d_si;
    int* cnt = seg == 0 ? deg_p : seg == 1 ? deg_d : seg == 2 ? scnt_p : scnt_d;
    const int n = seg == 0 ? EP : seg == 1 ? ED : seg == 2 ? SP : SD;
    const int nn = (seg == 0 || seg == 2) ? NP : ND;
    const int chunk = (nn + 7) >> 3;
    const int rlo = xcd * chunk;
    const int rhi = min(nn, rlo + chunk);
    for (int i = lb * 256 + tid; i < n; i += stride) {
      const int v = idx[i];
      if (v >= rlo && v < rhi) atomicAdd(&cnt[v], 1);
    }
  } else if (b < 1024 + 256) {
    const int lb = b - 1024;
    const int seg = lb >> 5;
    const float* W;
    int K;
    if (seg < 3) { W = convW_d + (size_t)seg * HID * HID; K = 128; }
    else if (seg < 6) { W = convW_p + (size_t)(seg - 3) * HID * HID; K = 128; }
    else if (seg == 6) { W = enc_Wd; K = 78; }
    else { W = enc_Wp; K = 70; }
    unsigned short* Whi = WhiAll + (size_t)seg * HID * HID;
    unsigned short* Wlo = WloAll + (size_t)seg * HID * HID;
    for (int i = (lb & 31) * 256 + tid; i < HID * HID; i += 32 * 256) {
      const int c = i >> 7, k = i & 127;
      const float v = (k < K) ? W[k * HID + c] : 0.f;
      const unsigned short hi = f2b(v);
      Whi[i] = hi;
      Wlo[i] = f2b(v - b2f(hi));
    }
  } else {
    const int lb = b - (1024 + 256);
    for (int i = lb * 256 + tid; i < 2 * vhalf; i += 128 * 256) {
      if (i < vhalf) vx_d[i] = emb_d[i & (HID - 1)] + d_feat[i];
      else { const int j = i - vhalf; vx_p[j] = emb_p[j & (HID - 1)] + p_feat[j]; }
    }
  }
}

// nrm + nb
__global__ void k_nrm_nb(const int* deg_d, float* nrm_d, int ND,
                         const int* deg_p, float* nrm_p, int NP,
                         const int* d_batch, float* nb_d,
                         const int* p_batch, float* nb_p, int B) {
  const int stride = gridDim.x * blockDim.x;
  const int total = ND + NP + 2 * B;
  for (int i = blockIdx.x * blockDim.x + threadIdx.x; i < total; i += stride) {
    if (i < ND) nrm_d[i] = rsqrtf((float)deg_d[i] + 1.0f);
    else if (i < ND + NP) { const int j = i - ND; nrm_p[j] = rsqrtf((float)deg_p[j] + 1.0f); }
    else if (i < ND + NP + B) {
      const int b = i - ND - NP;
      nb_d[b] = (float)(lowerb(d_batch, ND, b + 1) - lowerb(d_batch, ND, b));
    } else {
      const int b = i - ND - NP - B;
      nb_p[b] = (float)(lowerb(p_batch, NP, b + 1) - lowerb(p_batch, NP, b));
    }
  }
}

// segmented scan, 4 segments
__global__ __launch_bounds__(256)
void k_scan1_all(const int* c0, int* r0, int n0, int nb0,
                 const int* c1, int* r1, int n1, int nb1,
                 const int* c2, int* r2, int n2, int nb2,
                 const int* c3, int* r3, int n3, int nb3, int* aux) {
  __shared__ int sh[256];
  int b = blockIdx.x, seg = 0;
  if (b >= nb0) { b -= nb0; seg = 1; }
  if (seg == 1 && b >= nb1) { b -= nb1; seg = 2; }
  if (seg == 2 && b >= nb2) { b -= nb2; seg = 3; }
  const int* cnt = seg == 0 ? c0 : seg == 1 ? c1 : seg == 2 ? c2 : c3;
  int* row = seg == 0 ? r0 : seg == 1 ? r1 : seg == 2 ? r2 : r3;
  const int n = seg == 0 ? n0 : seg == 1 ? n1 : seg == 2 ? n2 : n3;
  const int tid = threadIdx.x;
  const int base = b * 1024 + tid * 4;
  int v0 = base + 0 < n ? cnt[base + 0] : 0;
  int v1 = base + 1 < n ? cnt[base + 1] : 0;
  int v2 = base + 2 < n ? cnt[base + 2] : 0;
  int v3 = base + 3 < n ? cnt[base + 3] : 0;
  const int s = v0 + v1 + v2 + v3;
  sh[tid] = s;
  __syncthreads();
  for (int o = 1; o < 256; o <<= 1) {
    const int t = (tid >= o) ? sh[tid - o] : 0;
    __syncthreads();
    sh[tid] += t;
    __syncthreads();
  }
  int excl = sh[tid] - s;
  if (tid == 255) aux[seg * 256 + b] = sh[255];
  if (base + 0 < n) row[base + 0] = excl; excl += v0;
  if (base + 1 < n) row[base + 1] = excl; excl += v1;
  if (base + 2 < n) row[base + 2] = excl; excl += v2;
  if (base + 3 < n) row[base + 3] = excl;
}

__global__ __launch_bounds__(256)
void k_scan2_all(int* aux, int nb0, int nb1, int nb2, int nb3) {
  __shared__ int sh[256];
  const int seg = blockIdx.x;
  const int nb = seg == 0 ? nb0 : seg == 1 ? nb1 : seg == 2 ? nb2 : nb3;
  int* a = aux + seg * 256;
  const int tid = threadIdx.x;
  const int v = tid < nb ? a[tid] : 0;
  sh[tid] = v;
  __syncthreads();
  for (int o = 1; o < 256; o <<= 1) {
    const int t = (tid >= o) ? sh[tid - o] : 0;
    __syncthreads();
    sh[tid] += t;
    __syncthreads();
  }
  if (tid < nb) a[tid] = sh[tid] - v;
}

__global__ __launch_bounds__(256)
void k_scan3_all(int* r0, int n0, int nb0, int t0, int* r1, int n1, int nb1, int t1,
                 int* r2, int n2, int nb2, int t2, int* r3, int n3, int nb3, int t3,
                 const int* aux) {
  int b = blockIdx.x, seg = 0;
  if (b >= nb0) { b -= nb0; seg = 1; }
  if (seg == 1 && b >= nb1) { b -= nb1; seg = 2; }
  if (seg == 2 && b >= nb2) { b -= nb2; seg = 3; }
  int* row = seg == 0 ? r0 : seg == 1 ? r1 : seg == 2 ? r2 : r3;
  const int n = seg == 0 ? n0 : seg == 1 ? n1 : seg == 2 ? n2 : n3;
  const int total = seg == 0 ? t0 : seg == 1 ? t1 : seg == 2 ? t2 : t3;
  const int add = aux[seg * 256 + b];
  const int base = b * 1024 + threadIdx.x * 4;
  #pragma unroll
  for (int k = 0; k < 4; ++k)
    if (base + k < n) row[base + k] += add;
  if (b == 0 && threadIdx.x == 0) row[n] = total;
}

// XCD-partitioned CSR fill
__global__ void k_fill_all(const int* p_src, const int* p_dst, const int* rowE_p, int* curE_p,
                           int* colE_p, int EP,
                           const int* d_src, const int* d_dst, const int* rowE_d, int* curE_d,
                           int* colE_d, int ED,
                           const int* p_sn, const int* p_si, const int* rowS_p, int* curS_p,
                           int* colS_p, int SP,
                           const int* d_sn, const int* d_si, const int* rowS_d, int* curS_d,
                           int* colS_d, int SD, int NP, int ND) {
  const int b = blockIdx.x;
  const int xcd = b & 7;
  const int rest = b >> 3;
  const int seg = rest & 3;
  const int lb = rest >> 2;
  const int stride = 64 * 256;
  const int start = lb * 256 + threadIdx.x;
  const int* key = seg == 0 ? p_dst : seg == 1 ? d_dst : seg == 2 ? p_si : d_si;
  const int* val = seg == 0 ? p_src : seg == 1 ? d_src : seg == 2 ? p_sn : d_sn;
  const int* row = seg == 0 ? rowE_p : seg == 1 ? rowE_d : seg == 2 ? rowS_p : rowS_d;
  int* cur = seg == 0 ? curE_p : seg == 1 ? curE_d : seg == 2 ? curS_p : curS_d;
  int* col = seg == 0 ? colE_p : seg == 1 ? colE_d : seg == 2 ? colS_p : colS_d;
  const int n = seg == 0 ? EP : seg == 1 ? ED : seg == 2 ? SP : SD;
  const int nn = (seg == 0 || seg == 2) ? NP : ND;
  const int chunk = (nn + 7) >> 3;
  const int rlo = xcd * chunk;
  const int rhi = min(nn, rlo + chunk);
  for (int i = start; i < n; i += stride) {
    const int k = key[i];
    if (k >= rlo && k < rhi)
      col[row[k] + atomicAdd(&cur[k], 1)] = val[i];
  }
}

// ---------------- conv GEMM (split-bf16 MFMA, G out bf16, fused BN stats) ----------------
__global__ __launch_bounds__(256, 2)
void k_gemm_both(const unsigned short* Zhi0, const unsigned short* Zlo0,
                 const unsigned short* Whi0, const unsigned short* Wlo0,
                 unsigned short* G0, int nbk0,
                 const unsigned short* Zhi1, const unsigned short* Zlo1,
                 const unsigned short* Whi1, const unsigned short* Wlo1,
                 unsigned short* G1, float* stats_sl) {
  __shared__ unsigned short Bt[128 * 132];
  __shared__ float lstats[256];
  const int bid = blockIdx.x;
  const bool isP = bid >= nbk0;
  const int lb = isP ? bid - nbk0 : bid;
  const unsigned short* Zhi = isP ? Zhi1 : Zhi0;
  const unsigned short* Zlo = isP ? Zlo1 : Zlo0;
  const unsigned short* Wthi = isP ? Whi1 : Whi0;
  const unsigned short* Wtlo = isP ? Wlo1 : Wlo0;
  unsigned short* G = isP ? G1 : G0;
  const int slice = (isP ? 32 : 0) + (lb & 31);

  const int tid = threadIdx.x;
  const int w = tid >> 6;
  const int l = tid & 63;
  const int l15 = l & 15;
  const int kb = l >> 4;

  for (int i = tid; i < 128 * 16; i += 256) {
    const int c = i >> 4, k8 = i & 15;
    *(bf16x8*)(&Bt[c * 132 + k8 * 8]) = *(const bf16x8*)(Wthi + (size_t)c * 128 + k8 * 8);
  }
  lstats[tid] = 0.f;

  const int rbase = lb * 128 + w * 32 + l15;
  bf16x8 ahi[2][4], alo[2][4];
  #pragma unroll
  for (int rt = 0; rt < 2; ++rt)
    #pragma unroll
    for (int ks = 0; ks < 4; ++ks) {
      ahi[rt][ks] = *(const bf16x8*)(Zhi + (size_t)(rbase + rt * 16) * 128 + ks * 32 + kb * 8);
      alo[rt][ks] = *(const bf16x8*)(Zlo + (size_t)(rbase + rt * 16) * 128 + ks * 32 + kb * 8);
    }

  f32x4v acc[2][8];
  #pragma unroll
  for (int rt = 0; rt < 2; ++rt)
    #pragma unroll
    for (int ct = 0; ct < 8; ++ct)
      acc[rt][ct] = (f32x4v){0.f, 0.f, 0.f, 0.f};

  __syncthreads();
  #pragma unroll
  for (int ks = 0; ks < 4; ++ks) {
    #pragma unroll
    for (int ct = 0; ct < 8; ++ct) {
      const bf16x8 b = *(const bf16x8*)(&Bt[(ct * 16 + l15) * 132 + ks * 32 + kb * 8]);
      acc[0][ct] = __builtin_amdgcn_mfma_f32_16x16x32_bf16(ahi[0][ks], b, acc[0][ct], 0, 0, 0);
      acc[1][ct] = __builtin_amdgcn_mfma_f32_16x16x32_bf16(ahi[1][ks], b, acc[1][ct], 0, 0, 0);
      acc[0][ct] = __builtin_amdgcn_mfma_f32_16x16x32_bf16(alo[0][ks], b, acc[0][ct], 0, 0, 0);
      acc[1][ct] = __builtin_amdgcn_mfma_f32_16x16x32_bf16(alo[1][ks], b, acc[1][ct], 0, 0, 0);
    }
  }
  __syncthreads();

  for (int i = tid; i < 128 * 16; i += 256) {
    const int c = i >> 4, k8 = i & 15;
    *(bf16x8*)(&Bt[c * 132 + k8 * 8]) = *(const bf16x8*)(Wtlo + (size_t)c * 128 + k8 * 8);
  }
  __syncthreads();
  #pragma unroll
  for (int ks = 0; ks < 4; ++ks) {
    #pragma unroll
    for (int ct = 0; ct < 8; ++ct) {
      const bf16x8 b = *(const bf16x8*)(&Bt[(ct * 16 + l15) * 132 + ks * 32 + kb * 8]);
      acc[0][ct] = __builtin_amdgcn_mfma_f32_16x16x32_bf16(ahi[0][ks], b, acc[0][ct], 0, 0, 0);
      acc[1][ct] = __builtin_amdgcn_mfma_f32_16x16x32_bf16(ahi[1][ks], b, acc[1][ct], 0, 0, 0);
    }
  }

  float csum[8], csq[8];
  #pragma unroll
  for (int ct = 0; ct < 8; ++ct) { csum[ct] = 0.f; csq[ct] = 0.f; }
  #pragma unroll
  for (int rt = 0; rt < 2; ++rt) {
    const size_t grow = (size_t)lb * 128 + w * 32 + rt * 16 + (l >> 4) * 4;
    #pragma unroll
    for (int j = 0; j < 4; ++j) {
      unsigned short* gr = G + (grow + j) * 128 + l15;
      #pragma unroll
      for (int ct = 0; ct < 8; ++ct) {
        const float v = acc[rt][ct][j];
        gr[ct * 16] = f2b(v);
        csum[ct] += v;
        csq[ct] += v * v;
      }
    }
  }
  #pragma unroll
  for (int ct = 0; ct < 8; ++ct) {
    csum[ct] += __shfl_xor(csum[ct], 16);
    csum[ct] += __shfl_xor(csum[ct], 32);
    csq[ct] += __shfl_xor(csq[ct], 16);
    csq[ct] += __shfl_xor(csq[ct], 32);
  }
  if (l < 16) {
    #pragma unroll
    for (int ct = 0; ct < 8; ++ct) {
      atomicAdd(&lstats[ct * 16 + l], csum[ct]);
      atomicAdd(&lstats[128 + ct * 16 + l], csq[ct]);
    }
  }
  __syncthreads();
  atomicAdd(&stats_sl[(size_t)slice * 256 + tid], lstats[tid]);
}

// ---------------- encoder GEMM: fp32 X loaded directly, split in registers ----------------
__global__ __launch_bounds__(256, 2)
void k_gemm_enc_direct(const float* X0, int K0,
                       const unsigned short* Whi0, const unsigned short* Wlo0,
                       const float* bias0, unsigned short* G0, int nbk0,
                       const float* X1, int K1,
                       const unsigned short* Whi1, const unsigned short* Wlo1,
                       const float* bias1, unsigned short* G1) {
  __shared__ unsigned short Bt[128 * 132];
  const int bid = blockIdx.x;
  const bool isP = bid >= nbk0;
  const int lb = isP ? bid - nbk0 : bid;
  const float* X = isP ? X1 : X0;
  const int K = isP ? K1 : K0;
  const unsigned short* Wthi = isP ? Whi1 : Whi0;
  const unsigned short* Wtlo = isP ? Wlo1 : Wlo0;
  const float* bias = isP ? bias1 : bias0;
  unsigned short* G = isP ? G1 : G0;

  const int tid = threadIdx.x;
  const int w = tid >> 6;
  const int l = tid & 63;
  const int l15 = l & 15;
  const int kb = l >> 4;

  for (int i = tid; i < 128 * 16; i += 256) {
    const int c = i >> 4, k8 = i & 15;
    *(bf16x8*)(&Bt[c * 132 + k8 * 8]) = *(const bf16x8*)(Wthi + (size_t)c * 128 + k8 * 8);
  }

  const int rbase = lb * 128 + w * 32 + l15;
  bf16x8 ahi[2][4], alo[2][4];
  #pragma unroll
  for (int rt = 0; rt < 2; ++rt) {
    const float* xr = X + (size_t)(rbase + rt * 16) * K;
    #pragma unroll
    for (int ks = 0; ks < 4; ++ks) {
      #pragma unroll
      for (int j = 0; j < 8; ++j) {
        const int k = ks * 32 + kb * 8 + j;
        const float v = (k < K) ? xr[k] : 0.f;
        const unsigned short hi = f2b(v);
        ahi[rt][ks][j] = (short)hi;
        alo[rt][ks][j] = (short)f2b(v - b2f(hi));
      }
    }
  }

  f32x4v acc[2][8];
  #pragma unroll
  for (int rt = 0; rt < 2; ++rt)
    #pragma unroll
    for (int ct = 0; ct < 8; ++ct)
      acc[rt][ct] = (f32x4v){0.f, 0.f, 0.f, 0.f};

  __syncthreads();
  #pragma unroll
  for (int ks = 0; ks < 4; ++ks) {
    #pragma unroll
    for (int ct = 0; ct < 8; ++ct) {
      const bf16x8 b = *(const bf16x8*)(&Bt[(ct * 16 + l15) * 132 + ks * 32 + kb * 8]);
      acc[0][ct] = __builtin_amdgcn_mfma_f32_16x16x32_bf16(ahi[0][ks], b, acc[0][ct], 0, 0, 0);
      acc[1][ct] = __builtin_amdgcn_mfma_f32_16x16x32_bf16(ahi[1][ks], b, acc[1][ct], 0, 0, 0);
      acc[0][ct] = __builtin_amdgcn_mfma_f32_16x16x32_bf16(alo[0][ks], b, acc[0][ct], 0, 0, 0);
      acc[1][ct] = __builtin_amdgcn_mfma_f32_16x16x32_bf16(alo[1][ks], b, acc[1][ct], 0, 0, 0);
    }
  }
  __syncthreads();

  for (int i = tid; i < 128 * 16; i += 256) {
    const int c = i >> 4, k8 = i & 15;
    *(bf16x8*)(&Bt[c * 132 + k8 * 8]) = *(const bf16x8*)(Wtlo + (size_t)c * 128 + k8 * 8);
  }
  __syncthreads();
  #pragma unroll
  for (int ks = 0; ks < 4; ++ks) {
    #pragma unroll
    for (int ct = 0; ct < 8; ++ct) {
      const bf16x8 b = *(const bf16x8*)(&Bt[(ct * 16 + l15) * 132 + ks * 32 + kb * 8]);
      acc[0][ct] = __builtin_amdgcn_mfma_f32_16x16x32_bf16(ahi[0][ks], b, acc[0][ct], 0, 0, 0);
      acc[1][ct] = __builtin_amdgcn_mfma_f32_16x16x32_bf16(ahi[1][ks], b, acc[1][ct], 0, 0, 0);
    }
  }

  float bb[8];
  #pragma unroll
  for (int ct = 0; ct < 8; ++ct) bb[ct] = bias[ct * 16 + l15];
  #pragma unroll
  for (int rt = 0; rt < 2; ++rt) {
    const size_t grow = (size_t)lb * 128 + w * 32 + rt * 16 + (l >> 4) * 4;
    #pragma unroll
    for (int j = 0; j < 4; ++j) {
      unsigned short* gr = G + (grow + j) * 128 + l15;
      #pragma unroll
      for (int ct = 0; ct < 8; ++ct)
        gr[ct * 16] = f2b(acc[rt][ct][j] + bb[ct]);
    }
  }
}

// fold stat slices -> scale/shift; re-zeros slices; also zeroes sum_S
__global__ __launch_bounds__(128)
void k_bn_scale_both(float* __restrict__ stats_sl,
                     const float* g0, const float* b0, float invN0, float* scsh0, float* zero0,
                     const float* g1, const float* b1, float invN1, float* scsh1, float* zero1,
                     int zn4) {
  const int seg = blockIdx.x;
  float* base = stats_sl + (size_t)seg * 32 * 256;
  const float* g = seg ? g1 : g0;
  const float* bb = seg ? b1 : b0;
  const float invN = seg ? invN1 : invN0;
  float* scsh = seg ? scsh1 : scsh0;
  float* zero = seg ? zero1 : zero0;
  const int c = threadIdx.x;
  float s = 0.f, ss = 0.f;
  for (int k = 0; k < 32; ++k) {
    s += base[(size_t)k * 256 + c];
    ss += base[(size_t)k * 256 + 128 + c];
    base[(size_t)k * 256 + c] = 0.f;
    base[(size_t)k * 256 + 128 + c] = 0.f;
  }
  const float m = s * invN;
  const float var = ss * invN - m * m;
  const float sc = g[c] * rsqrtf(var + 1e-5f);
  scsh[c] = sc;
  scsh[HID + c] = bb[c] - m * sc;
  const float4 z = {0.f, 0.f, 0.f, 0.f};
  for (int i = c; i < zn4; i += 128) ((float4*)zero)[i] = z;
}

// fused upass+agg, 16-lane row groups (16 nodes/block, 16B bf16x8 loads)
template<bool HASF>
__global__ __launch_bounds__(256)
void k_agg_both(const int* rE0, const int* cE0, const unsigned short* G0,
                const float* scsh0, const int* bat0, const float* vx0, const float* nrm0,
                unsigned short* Zhi0, unsigned short* Zlo0, int nbk0,
                const int* rE1, const int* cE1, const unsigned short* G1,
                const float* scsh1, const int* bat1, const float* vx1, const float* nrm1,
                unsigned short* Zhi1, unsigned short* Zlo1) {
  const int bid = blockIdx.x;
  const bool isP = bid >= nbk0;
  const int lb = isP ? bid - nbk0 : bid;
  const int* rowp = isP ? rE1 : rE0;
  const int* colp = isP ? cE1 : cE0;
  const unsigned short* G = isP ? G1 : G0;
  const float* scsh = isP ? scsh1 : scsh0;
  const int* batch = isP ? bat1 : bat0;
  const float* vx = isP ? vx1 : vx0;
  const float* nrm = isP ? nrm1 : nrm0;
  unsigned short* Zhi = isP ? Zhi1 : Zhi0;
  unsigned short* Zlo = isP ? Zlo1 : Zlo0;

  const int tid = threadIdx.x;
  const int node = lb * 16 + (tid >> 4);
  const int c8 = tid & 15;
  float sc8[8], sh8[8];
  if constexpr (HASF) {
    const float4 a0 = *(const float4*)(scsh + c8 * 8);
    const float4 a1 = *(const float4*)(scsh + c8 * 8 + 4);
    const float4 b0 = *(const float4*)(scsh + HID + c8 * 8);
    const float4 b1 = *(const float4*)(scsh + HID + c8 * 8 + 4);
    sc8[0] = a0.x; sc8[1] = a0.y; sc8[2] = a0.z; sc8[3] = a0.w;
    sc8[4] = a1.x; sc8[5] = a1.y; sc8[6] = a1.z; sc8[7] = a1.w;
    sh8[0] = b0.x; sh8[1] = b0.y; sh8[2] = b0.z; sh8[3] = b0.w;
    sh8[4] = b1.x; sh8[5] = b1.y; sh8[6] = b1.z; sh8[7] = b1.w;
  }
  auto loadU = [&](int i, float* u) {
    const bf16x8 raw = *(const bf16x8*)(G + (size_t)i * HID + c8 * 8);
    const float* vrow = vx + (size_t)batch[i] * HID + c8 * 8;
    const float4 va = *(const float4*)vrow;
    const float4 vb = *(const float4*)(vrow + 4);
    const float vv[8] = {va.x, va.y, va.z, va.w, vb.x, vb.y, vb.z, vb.w};
    #pragma unroll
    for (int k = 0; k < 8; ++k) {
      float f = b2f((unsigned short)raw[k]);
      if constexpr (HASF) f = fmaxf(f * sc8[k] + sh8[k], 0.f);
      u[k] = f + vv[k];
    }
  };
  const int lo = rowp[node], hi = rowp[node + 1];
  const float nv = nrm[node];
  const float s2 = nv * nv;
  float acc[8];
  loadU(node, acc);
  #pragma unroll
  for (int k = 0; k < 8; ++k) acc[k] *= s2;
  int e = lo;
  for (; e + 4 <= hi; e += 4) {
    const int i0 = colp[e], i1 = colp[e + 1], i2 = colp[e + 2], i3 = colp[e + 3];
    const float w0 = nrm[i0] * nv, w1 = nrm[i1] * nv, w2 = nrm[i2] * nv, w3 = nrm[i3] * nv;
    float u0[8], u1[8], u2[8], u3[8];
    loadU(i0, u0);
    loadU(i1, u1);
    loadU(i2, u2);
    loadU(i3, u3);
    #pragma unroll
    for (int k = 0; k < 8; ++k)
      acc[k] += u0[k] * w0 + u1[k] * w1 + u2[k] * w2 + u3[k] * w3;
  }
  for (; e < hi; ++e) {
    const int i0 = colp[e];
    const float w = nrm[i0] * nv;
    float u[8];
    loadU(i0, u);
    #pragma unroll
    for (int k = 0; k < 8; ++k) acc[k] += u[k] * w;
  }
  bf16x8 h, l8;
  #pragma unroll
  for (int k = 0; k < 8; ++k) {
    const unsigned short hs = f2b(acc[k]);
    h[k] = (short)hs;
    l8[k] = (short)f2b(acc[k] - b2f(hs));
  }
  *(bf16x8*)(Zhi + (size_t)node * HID + c8 * 8) = h;
  *(bf16x8*)(Zlo + (size_t)node * HID + c8 * 8) = l8;
}

// fused sub-gather + batch pooling, 16-lane row groups (16 nodes/block)
__global__ __launch_bounds__(256)
void k_sub_pool_both(const int* rS0, const int* cS0, const unsigned short* G0, const float* scsh0,
                     const int* bat0, float* sumS0, int nbk0,
                     const int* rS1, const int* cS1, const unsigned short* G1, const float* scsh1,
                     const int* bat1, float* sumS1) {
  __shared__ float sh[16][HID];
  __shared__ int batl[16];
  const int bid = blockIdx.x;
  const bool isP = bid >= nbk0;
  const int lb = isP ? bid - nbk0 : bid;
  const int* rowp = isP ? rS1 : rS0;
  const int* colp = isP ? cS1 : cS0;
  const unsigned short* G = isP ? G1 : G0;
  const float* scsh = isP ? scsh1 : scsh0;
  const int* batch = isP ? bat1 : bat0;
  float* sumS = isP ? sumS1 : sumS0;

  const int tid = threadIdx.x;
  const int grp = tid >> 4;
  const int node = lb * 16 + grp;
  const int c8 = tid & 15;
  float sc8[8], sh8[8];
  {
    const float4 a0 = *(const float4*)(scsh + c8 * 8);
    const float4 a1 = *(const float4*)(scsh + c8 * 8 + 4);
    const float4 b0 = *(const float4*)(scsh + HID + c8 * 8);
    const float4 b1 = *(const float4*)(scsh + HID + c8 * 8 + 4);
    sc8[0] = a0.x; sc8[1] = a0.y; sc8[2] = a0.z; sc8[3] = a0.w;
    sc8[4] = a1.x; sc8[5] = a1.y; sc8[6] = a1.z; sc8[7] = a1.w;
    sh8[0] = b0.x; sh8[1] = b0.y; sh8[2] = b0.z; sh8[3] = b0.w;
    sh8[4] = b1.x; sh8[5] = b1.y; sh8[6] = b1.z; sh8[7] = b1.w;
  }
  auto loadR = [&](int i, float* u) {
    const bf16x8 raw = *(const bf16x8*)(G + (size_t)i * HID + c8 * 8);
    #pragma unroll
    for (int k = 0; k < 8; ++k)
      u[k] = fmaxf(b2f((unsigned short)raw[k]) * sc8[k] + sh8[k], 0.f);
  };
  const int lo = rowp[node], hi = rowp[node + 1];
  float acc[8];
  #pragma unroll
  for (int k = 0; k < 8; ++k) acc[k] = 0.f;
  int e = lo;
  for (; e + 4 <= hi; e += 4) {
    float u0[8], u1[8], u2[8], u3[8];
    loadR(colp[e], u0);
    loadR(colp[e + 1], u1);
    loadR(colp[e + 2], u2);
    loadR(colp[e + 3], u3);
    #pragma unroll
    for (int k = 0; k < 8; ++k) acc[k] += (u0[k] + u1[k]) + (u2[k] + u3[k]);
  }
  for (; e < hi; ++e) {
    float u[8];
    loadR(colp[e], u);
    #pragma unroll
    for (int k = 0; k < 8; ++k) acc[k] += u[k];
  }
  const float inv = 1.0f / fmaxf((float)(hi - lo), 1.0f);
  #pragma unroll
  for (int k = 0; k < 8; ++k) sh[grp][c8 * 8 + k] = acc[k] * inv;
  if (tid < 16) batl[tid] = batch[lb * 16 + tid];
  __syncthreads();
  if (tid < HID) {
    int cur = batl[0];
    float a = 0.f;
    #pragma unroll
    for (int g = 0; g < 16; ++g) {
      if (batl[g] != cur) {
        atomicAdd(&sumS[(size_t)cur * HID + tid], a);
        a = 0.f;
        cur = batl[g];
      }
      a += sh[g][tid];
    }
    atomicAdd(&sumS[(size_t)cur * HID + tid], a);
  }
}

// vn update for both graphs (grid 2B)
__global__ __launch_bounds__(128)
void k_vn_update_both(const float* ps0, float* vx0, const float* W0, const float* b0,
                      const float* ps1, float* vx1, const float* W1, const float* b1, int B) {
  const int gb = blockIdx.x;
  const bool isP = gb >= B;
  const int b = isP ? gb - B : gb;
  const float* pooledSum = isP ? ps1 : ps0;
  float* vx = isP ? vx1 : vx0;
  const float* W = isP ? W1 : W0;
  const float* bias = isP ? b1 : b0;
  const int c = threadIdx.x;
  __shared__ float xin[HID];
  xin[c] = pooledSum[(size_t)b * HID + c] + vx[(size_t)b * HID + c];
  __syncthreads();
  float acc = bias[c];
  #pragma unroll 8
  for (int k = 0; k < HID; k += 4) {
    const float4 x = *(const float4*)&xin[k];
    acc += x.x * W[k * HID + c] + x.y * W[(k + 1) * HID + c]
         + x.z * W[(k + 2) * HID + c] + x.w * W[(k + 3) * HID + c];
  }
  vx[(size_t)b * HID + c] += fmaxf(acc, 0.0f);
}

// final MLP with inline cross-modal A computation
__global__ __launch_bounds__(128)
void k_final_mlp_both(const float* sum_Sd, const float* sum_Sp,
                      const float* nb_d, const float* nb_p,
                      const float* f0, const float* W0, const float* b0,
                      const float* f1, const float* W1, const float* b1,
                      float* __restrict__ fpre, int B) {
  const int gb = blockIdx.x;
  const bool isP = gb >= B;
  const int b = isP ? gb - B : gb;
  const float* feat = isP ? f1 : f0;
  const float* W = isP ? W1 : W0;
  const float* bias = isP ? b1 : b0;
  const int c = threadIdx.x;
  __shared__ float xin[2 * HID];
  const float nd = nb_d[b], np_ = nb_p[b];
  const float md = sum_Sd[(size_t)b * HID + c] / fmaxf(nd, 1.f);
  const float mp = sum_Sp[(size_t)b * HID + c] / fmaxf(np_, 1.f);
  xin[c] = isP ? (mp + (np_ > 0.f ? md : 0.f)) : (md + (nd > 0.f ? mp : 0.f));
  xin[HID + c] = feat[(size_t)b * HID + c];
  __syncthreads();
  float acc = bias[c];
  #pragma unroll 8
  for (int k = 0; k < 2 * HID; k += 4) {
    const float4 x = *(const float4*)&xin[k];
    acc += x.x * W[k * HID + c] + x.y * W[(k + 1) * HID + c]
         + x.z * W[(k + 2) * HID + c] + x.w * W[(k + 3) * HID + c];
  }
  fpre[(size_t)gb * HID + c] = acc;
}

__global__ __launch_bounds__(256)
void k_bn_stats_both(const float* __restrict__ fpre, float* __restrict__ statsF, int B) {
  __shared__ float sh[2][256];
  const int seg = blockIdx.x >= 128 ? 1 : 0;
  const int lb = blockIdx.x - seg * 128;
  const float* X = fpre + (size_t)seg * B * HID;
  float* stats = statsF + seg * 256;
  const int tid = threadIdx.x;
  const int c = tid & (HID - 1);
  const int half = tid >> 7;
  float s = 0.f, ss = 0.f;
  for (int r = lb * 2 + half; r < B; r += 256) {
    const float v = X[(size_t)r * HID + c];
    s += v; ss += v * v;
  }
  sh[0][tid] = s; sh[1][tid] = ss;
  __syncthreads();
  if (tid < HID) {
    atomicAdd(&stats[c], sh[0][tid] + sh[0][tid + 128]);
    atomicAdd(&stats[HID + c], sh[1][tid] + sh[1][tid + 128]);
  }
}

__global__ void k_bn_apply_both(const float* __restrict__ fpre, float* __restrict__ out,
                                const float* __restrict__ statsF,
                                const float* g0, const float* b0,
                                const float* g1, const float* b1, int B, float invN) {
  const int stride = gridDim.x * blockDim.x;
  const int n4 = 2 * B * 32;
  for (int i = blockIdx.x * blockDim.x + threadIdx.x; i < n4; i += stride) {
    const int seg = i >= B * 32 ? 1 : 0;
    const int c4 = i & 31;
    const float* stats = statsF + seg * 256;
    const float4 m4 = ((const float4*)stats)[c4];
    const float4 q4 = ((const float4*)stats)[32 + c4];
    const float4 g4 = ((const float4*)(seg ? g1 : g0))[c4];
    const float4 b4 = ((const float4*)(seg ? b1 : b0))[c4];
    float4 v = ((const float4*)fpre)[i];
    float m, va;
    m = m4.x * invN; va = q4.x * invN - m * m; v.x = (v.x - m) * rsqrtf(va + 1e-5f) * g4.x + b4.x;
    m = m4.y * invN; va = q4.y * invN - m * m; v.y = (v.y - m) * rsqrtf(va + 1e-5f) * g4.y + b4.y;
    m = m4.z * invN; va = q4.z * invN - m * m; v.z = (v.z - m) * rsqrtf(va + 1e-5f) * g4.z + b4.z;
    m = m4.w * invN; va = q4.w * invN - m * m; v.w = (v.w - m) * rsqrtf(va + 1e-5f) * g4.w + b4.w;
    ((float4*)out)[i] = v;
  }
}

// ---------------- host launch ----------------
extern "C" void kernel_launch(void* const* d_in, const int* in_sizes, int n_in,
                              void* d_out, int out_size, void* d_ws, size_t ws_size,
                              hipStream_t stream) {
  const float* drug_x   = (const float*)d_in[0];
  const float* prot_x   = (const float*)d_in[1];
  const float* d_feat   = (const float*)d_in[2];
  const float* p_feat   = (const float*)d_in[3];
  const int*   d_ei     = (const int*)d_in[4];
  const int*   d_batch  = (const int*)d_in[5];
  const int*   d_sn     = (const int*)d_in[6];
  const int*   d_si     = (const int*)d_in[7];
  const int*   p_ei     = (const int*)d_in[8];
  const int*   p_batch  = (const int*)d_in[9];
  const int*   p_sn     = (const int*)d_in[10];
  const int*   p_si     = (const int*)d_in[11];
  const float* enc_Wd   = (const float*)d_in[12];
  const float* enc_bd   = (const float*)d_in[13];
  const float* enc_Wp   = (const float*)d_in[14];
  const float* enc_bp   = (const float*)d_in[15];
  const float* convW_d  = (const float*)d_in[16];
  const float* convW_p  = (const float*)d_in[18];
  const float* bng_d    = (const float*)d_in[20];
  const float* bnb_d    = (const float*)d_in[21];
  const float* bng_p    = (const float*)d_in[22];
  const float* bnb_p    = (const float*)d_in[23];
  const float* vn_emb_d = (const float*)d_in[24];
  const float* vn_emb_p = (const float*)d_in[25];
  const float* vnW_d    = (const float*)d_in[26];
  const float* vnb_d    = (const float*)d_in[27];
  const float* vnW_p    = (const float*)d_in[28];
  const float* vnb_p    = (const float*)d_in[29];
  const float* mlpd1_W  = (const float*)d_in[30];
  const float* mlpd1_b  = (const float*)d_in[31];
  const float* mlpd1_g  = (const float*)d_in[32];
  const float* mlpd1_be = (const float*)d_in[33];
  const float* mlpp1_W  = (const float*)d_in[34];
  const float* mlpp1_b  = (const float*)d_in[35];
  const float* mlpp1_g  = (const float*)d_in[36];
  const float* mlpp1_be = (const float*)d_in[37];

  const int ND = in_sizes[5];
  const int ED = in_sizes[4] / 2;
  const int SD = in_sizes[6];
  const int NP = in_sizes[9];
  const int EP = in_sizes[8] / 2;
  const int SP = in_sizes[10];
  const int B  = in_sizes[2] / HID;
  (void)n_in; (void)out_size; (void)ws_size;

  char* wsb = (char*)d_ws;
  size_t off = 0;
  auto alloc = [&](size_t bytes) -> void* {
    void* p = (void*)(wsb + off);
    off = (off + bytes + 255) & ~(size_t)255;
    return p;
  };
  // node buffers (G and Z bf16)
  unsigned short* Gp = (unsigned short*)alloc((size_t)NP * HID * 2);
  unsigned short* Zhi_p = (unsigned short*)alloc((size_t)NP * HID * 2);
  unsigned short* Zlo_p = (unsigned short*)alloc((size_t)NP * HID * 2);
  unsigned short* Gd = (unsigned short*)alloc((size_t)ND * HID * 2);
  unsigned short* Zhi_d = (unsigned short*)alloc((size_t)ND * HID * 2);
  unsigned short* Zlo_d = (unsigned short*)alloc((size_t)ND * HID * 2);
  unsigned short* WhiAll = (unsigned short*)alloc((size_t)8 * HID * HID * 2);
  unsigned short* WloAll = (unsigned short*)alloc((size_t)8 * HID * HID * 2);
  // CSR
  float* nrm_p = (float*)alloc((size_t)NP * 4);
  float* nrm_d = (float*)alloc((size_t)ND * 4);
  int* rowE_p = (int*)alloc((size_t)(NP + 1) * 4);
  int* rowE_d = (int*)alloc((size_t)(ND + 1) * 4);
  int* rowS_p = (int*)alloc((size_t)(NP + 1) * 4);
  int* rowS_d = (int*)alloc((size_t)(ND + 1) * 4);
  int* colE_p = (int*)alloc((size_t)EP * 4);
  int* colE_d = (int*)alloc((size_t)ED * 4);
  int* colS_p = (int*)alloc((size_t)SP * 4);
  int* colS_d = (int*)alloc((size_t)SD * 4);
  int* aux    = (int*)alloc(4 * 256 * 4);
  float* vx_d  = (float*)alloc((size_t)B * HID * 4);
  float* vx_p  = (float*)alloc((size_t)B * HID * 4);
  float* sum_Sd = (float*)alloc((size_t)B * HID * 4);
  float* sum_Sp = (float*)alloc((size_t)B * HID * 4);
  float* nb_d  = (float*)alloc((size_t)B * 4);
  float* nb_p  = (float*)alloc((size_t)B * 4);
  float* scsh_d = (float*)alloc(2 * HID * 4);
  float* scsh_p = (float*)alloc(2 * HID * 4);
  float* fpre  = (float*)alloc((size_t)2 * B * HID * 4);
  float* statsF = (float*)alloc(2 * 256 * 4);
  // zero region
  const size_t zstart = off;
  int* deg_p  = (int*)alloc((size_t)NP * 4);
  int* deg_d  = (int*)alloc((size_t)ND * 4);
  int* scnt_p = (int*)alloc((size_t)NP * 4);
  int* scnt_d = (int*)alloc((size_t)ND * 4);
  int* curE_p = (int*)alloc((size_t)NP * 4);
  int* curE_d = (int*)alloc((size_t)ND * 4);
  int* curS_p = (int*)alloc((size_t)NP * 4);
  int* curS_d = (int*)alloc((size_t)ND * 4);
  float* stats_sl = (float*)alloc((size_t)64 * 256 * 4);
  const size_t zend = off;

  const int* d_src = d_ei;  const int* d_dst = d_ei + ED;
  const int* p_src = p_ei;  const int* p_dst = p_ei + EP;

  // ---- memset + merged prep (XCD-partitioned hist) ----
  hipMemsetAsync(wsb + zstart, 0, zend - zstart, stream);
  k_prep1<<<1024 + 256 + 128, 256, 0, stream>>>(
      p_dst, EP, deg_p, d_dst, ED, deg_d, p_si, SP, scnt_p, d_si, SD, scnt_d,
      NP, ND,
      convW_d, convW_p, enc_Wd, enc_Wp, WhiAll, WloAll,
      vn_emb_d, d_feat, vx_d, vn_emb_p, p_feat, vx_p, B * HID);
  k_nrm_nb<<<1024, 256, 0, stream>>>(deg_d, nrm_d, ND, deg_p, nrm_p, NP,
                                     d_batch, nb_d, p_batch, nb_p, B);
  const int nbP = (NP + 1023) / 1024, nbD = (ND + 1023) / 1024;
  k_scan1_all<<<2 * nbP + 2 * nbD, 256, 0, stream>>>(
      deg_p, rowE_p, NP, nbP, deg_d, rowE_d, ND, nbD,
      scnt_p, rowS_p, NP, nbP, scnt_d, rowS_d, ND, nbD, aux);
  k_scan2_all<<<4, 256, 0, stream>>>(aux, nbP, nbD, nbP, nbD);
  k_scan3_all<<<2 * nbP + 2 * nbD, 256, 0, stream>>>(
      rowE_p, NP, nbP, EP, rowE_d, ND, nbD, ED,
      rowS_p, NP, nbP, SP, rowS_d, ND, nbD, SD, aux);
  k_fill_all<<<2048, 256, 0, stream>>>(
      p_src, p_dst, rowE_p, curE_p, colE_p, EP,
      d_src, d_dst, rowE_d, curE_d, colE_d, ED,
      p_sn, p_si, rowS_p, curS_p, colS_p, SP,
      d_sn, d_si, rowS_d, curS_d, colS_d, SD, NP, ND);

  // ---- encoder GEMM with in-register fp32->split-bf16 conversion ----
  k_gemm_enc_direct<<<ND / 128 + NP / 128, 256, 0, stream>>>(
      drug_x, 78, WhiAll + (size_t)6 * HID * HID, WloAll + (size_t)6 * HID * HID,
      enc_bd, Gd, ND / 128,
      prot_x, 70, WhiAll + (size_t)7 * HID * HID, WloAll + (size_t)7 * HID * HID,
      enc_bp, Gp);

  for (int l = 0; l < 3; ++l) {
    if (l == 0)
      k_agg_both<false><<<ND / 16 + NP / 16, 256, 0, stream>>>(
          rowE_d, colE_d, Gd, nullptr, d_batch, vx_d, nrm_d, Zhi_d, Zlo_d, ND / 16,
          rowE_p, colE_p, Gp, nullptr, p_batch, vx_p, nrm_p, Zhi_p, Zlo_p);
    else
      k_agg_both<true><<<ND / 16 + NP / 16, 256, 0, stream>>>(
          rowE_d, colE_d, Gd, scsh_d, d_batch, vx_d, nrm_d, Zhi_d, Zlo_d, ND / 16,
          rowE_p, colE_p, Gp, scsh_p, p_batch, vx_p, nrm_p, Zhi_p, Zlo_p);
    k_gemm_both<<<ND / 128 + NP / 128, 256, 0, stream>>>(
        Zhi_d, Zlo_d, WhiAll + (size_t)l * HID * HID, WloAll + (size_t)l * HID * HID,
        Gd, ND / 128,
        Zhi_p, Zlo_p, WhiAll + (size_t)(3 + l) * HID * HID, WloAll + (size_t)(3 + l) * HID * HID,
        Gp, stats_sl);
    k_bn_scale_both<<<2, 128, 0, stream>>>(stats_sl,
        bng_d + l * HID, bnb_d + l * HID, 1.0f / (float)ND, scsh_d, sum_Sd,
        bng_p + l * HID, bnb_p + l * HID, 1.0f / (float)NP, scsh_p, sum_Sp,
        B * HID / 4);
    k_sub_pool_both<<<ND / 16 + NP / 16, 256, 0, stream>>>(
        rowS_d, colS_d, Gd, scsh_d, d_batch, sum_Sd, ND / 16,
        rowS_p, colS_p, Gp, scsh_p, p_batch, sum_Sp);
    if (l < 2)
      k_vn_update_both<<<2 * B, 128, 0, stream>>>(
          sum_Sd, vx_d, vnW_d + (size_t)l * HID * HID, vnb_d + l * HID,
          sum_Sp, vx_p, vnW_p + (size_t)l * HID * HID, vnb_p + l * HID, B);
  }

  // ---- final ----
  k_final_mlp_both<<<2 * B, 128, 0, stream>>>(sum_Sd, sum_Sp, nb_d, nb_p,
                                              d_feat, mlpd1_W, mlpd1_b,
                                              p_feat, mlpp1_W, mlpp1_b, fpre, B);
  hipMemsetAsync(statsF, 0, 2 * 256 * 4, stream);
  k_bn_stats_both<<<256, 256, 0, stream>>>(fpre, statsF, B);
  k_bn_apply_both<<<128, 256, 0, stream>>>(fpre, (float*)d_out, statsF,
                                           mlpd1_g, mlpd1_be, mlpp1_g, mlpp1_be,
                                           B, 1.0f / (float)B);
}

// Round 15
// 626.967 us; speedup vs baseline: 1.0198x; 1.0198x over previous
//
#include <hip/hip_runtime.h>
#include <cstdint>
#include <cstddef>

#define HID 128
#define HB 1024

using bf16x8 = __attribute__((ext_vector_type(8))) short;
using f32x4v = __attribute__((ext_vector_type(4))) float;

// ---------------- bf16 helpers (RNE) ----------------
static __device__ __forceinline__ unsigned short f2b(float x) {
  unsigned int u = __float_as_uint(x);
  unsigned int r = u + 0x7FFFu + ((u >> 16) & 1u);
  return (unsigned short)(r >> 16);
}
static __device__ __forceinline__ float b2f(unsigned short h) {
  return __uint_as_float(((unsigned int)h) << 16);
}
static __device__ __forceinline__ float4 b2f4(ushort4 h) {
  return make_float4(b2f(h.x), b2f(h.y), b2f(h.z), b2f(h.w));
}

static __device__ __forceinline__ int lowerb(const int* __restrict__ a, int n, int v) {
  int lo = 0, hi = n;
  while (lo < hi) { int m = (lo + hi) >> 1; if (a[m] < v) lo = m + 1; else hi = m; }
  return lo;
}

// ---------------- prep1: hist(4seg) + wcvt + vx_init, one launch ----------------
__global__ __launch_bounds__(256)
void k_prep1(const int* p_dst, int EP, int* deg_p, const int* d_dst, int ED, int* deg_d,
             const int* p_si, int SP, int* scnt_p, const int* d_si, int SD, int* scnt_d,
             const float* convW_d, const float* convW_p,
             const float* enc_Wd, const float* enc_Wp,
             unsigned short* WhiAll, unsigned short* WloAll,
             const float* emb_d, const float* d_feat, float* vx_d,
             const float* emb_p, const float* p_feat, float* vx_p, int vhalf) {
  const int b = blockIdx.x;
  const int tid = threadIdx.x;
  if (b < 4 * HB) {
    const int seg = b & 3, lb = b >> 2;
    const int stride = HB * 256;
    const int* idx = seg == 0 ? p_dst : seg == 1 ? d_dst : seg == 2 ? p_si : d_si;
    int* cnt = seg == 0 ? deg_p : seg == 1 ? deg_d : seg == 2 ? scnt_p : scnt_d;
    const int n = seg == 0 ? EP : seg == 1 ? ED : seg == 2 ? SP : SD;
    for (int i = lb * 256 + tid; i < n; i += stride) atomicAdd(&cnt[idx[i]], 1);
  } else if (b < 4 * HB + 256) {
    const int lb = b - 4 * HB;
    const int seg = lb >> 5;
    const float* W;
    int K;
    if (seg < 3) { W = convW_d + (size_t)seg * HID * HID; K = 128; }
    else if (seg < 6) { W = convW_p + (size_t)(seg - 3) * HID * HID; K = 128; }
    else if (seg == 6) { W = enc_Wd; K = 78; }
    else { W = enc_Wp; K = 70; }
    unsigned short* Whi = WhiAll + (size_t)seg * HID * HID;
    unsigned short* Wlo = WloAll + (size_t)seg * HID * HID;
    for (int i = (lb & 31) * 256 + tid; i < HID * HID; i += 32 * 256) {
      const int c = i >> 7, k = i & 127;
      const float v = (k < K) ? W[k * HID + c] : 0.f;
      const unsigned short hi = f2b(v);
      Whi[i] = hi;
      Wlo[i] = f2b(v - b2f(hi));
    }
  } else {
    const int lb = b - (4 * HB + 256);
    for (int i = lb * 256 + tid; i < 2 * vhalf; i += 128 * 256) {
      if (i < vhalf) vx_d[i] = emb_d[i & (HID - 1)] + d_feat[i];
      else { const int j = i - vhalf; vx_p[j] = emb_p[j & (HID - 1)] + p_feat[j]; }
    }
  }
}

// nrm + nb
__global__ void k_nrm_nb(const int* deg_d, float* nrm_d, int ND,
                         const int* deg_p, float* nrm_p, int NP,
                         const int* d_batch, float* nb_d,
                         const int* p_batch, float* nb_p, int B) {
  const int stride = gridDim.x * blockDim.x;
  const int total = ND + NP + 2 * B;
  for (int i = blockIdx.x * blockDim.x + threadIdx.x; i < total; i += stride) {
    if (i < ND) nrm_d[i] = rsqrtf((float)deg_d[i] + 1.0f);
    else if (i < ND + NP) { const int j = i - ND; nrm_p[j] = rsqrtf((float)deg_p[j] + 1.0f); }
    else if (i < ND + NP + B) {
      const int b = i - ND - NP;
      nb_d[b] = (float)(lowerb(d_batch, ND, b + 1) - lowerb(d_batch, ND, b));
    } else {
      const int b = i - ND - NP - B;
      nb_p[b] = (float)(lowerb(p_batch, NP, b + 1) - lowerb(p_batch, NP, b));
    }
  }
}

// segmented scan, 4 segments
__global__ __launch_bounds__(256)
void k_scan1_all(const int* c0, int* r0, int n0, int nb0,
                 const int* c1, int* r1, int n1, int nb1,
                 const int* c2, int* r2, int n2, int nb2,
                 const int* c3, int* r3, int n3, int nb3, int* aux) {
  __shared__ int sh[256];
  int b = blockIdx.x, seg = 0;
  if (b >= nb0) { b -= nb0; seg = 1; }
  if (seg == 1 && b >= nb1) { b -= nb1; seg = 2; }
  if (seg == 2 && b >= nb2) { b -= nb2; seg = 3; }
  const int* cnt = seg == 0 ? c0 : seg == 1 ? c1 : seg == 2 ? c2 : c3;
  int* row = seg == 0 ? r0 : seg == 1 ? r1 : seg == 2 ? r2 : r3;
  const int n = seg == 0 ? n0 : seg == 1 ? n1 : seg == 2 ? n2 : n3;
  const int tid = threadIdx.x;
  const int base = b * 1024 + tid * 4;
  int v0 = base + 0 < n ? cnt[base + 0] : 0;
  int v1 = base + 1 < n ? cnt[base + 1] : 0;
  int v2 = base + 2 < n ? cnt[base + 2] : 0;
  int v3 = base + 3 < n ? cnt[base + 3] : 0;
  const int s = v0 + v1 + v2 + v3;
  sh[tid] = s;
  __syncthreads();
  for (int o = 1; o < 256; o <<= 1) {
    const int t = (tid >= o) ? sh[tid - o] : 0;
    __syncthreads();
    sh[tid] += t;
    __syncthreads();
  }
  int excl = sh[tid] - s;
  if (tid == 255) aux[seg * 256 + b] = sh[255];
  if (base + 0 < n) row[base + 0] = excl; excl += v0;
  if (base + 1 < n) row[base + 1] = excl; excl += v1;
  if (base + 2 < n) row[base + 2] = excl; excl += v2;
  if (base + 3 < n) row[base + 3] = excl;
}

__global__ __launch_bounds__(256)
void k_scan2_all(int* aux, int nb0, int nb1, int nb2, int nb3) {
  __shared__ int sh[256];
  const int seg = blockIdx.x;
  const int nb = seg == 0 ? nb0 : seg == 1 ? nb1 : seg == 2 ? nb2 : nb3;
  int* a = aux + seg * 256;
  const int tid = threadIdx.x;
  const int v = tid < nb ? a[tid] : 0;
  sh[tid] = v;
  __syncthreads();
  for (int o = 1; o < 256; o <<= 1) {
    const int t = (tid >= o) ? sh[tid - o] : 0;
    __syncthreads();
    sh[tid] += t;
    __syncthreads();
  }
  if (tid < nb) a[tid] = sh[tid] - v;
}

__global__ __launch_bounds__(256)
void k_scan3_all(int* r0, int n0, int nb0, int t0, int* r1, int n1, int nb1, int t1,
                 int* r2, int n2, int nb2, int t2, int* r3, int n3, int nb3, int t3,
                 const int* aux) {
  int b = blockIdx.x, seg = 0;
  if (b >= nb0) { b -= nb0; seg = 1; }
  if (seg == 1 && b >= nb1) { b -= nb1; seg = 2; }
  if (seg == 2 && b >= nb2) { b -= nb2; seg = 3; }
  int* row = seg == 0 ? r0 : seg == 1 ? r1 : seg == 2 ? r2 : r3;
  const int n = seg == 0 ? n0 : seg == 1 ? n1 : seg == 2 ? n2 : n3;
  const int total = seg == 0 ? t0 : seg == 1 ? t1 : seg == 2 ? t2 : t3;
  const int add = aux[seg * 256 + b];
  const int base = b * 1024 + threadIdx.x * 4;
  #pragma unroll
  for (int k = 0; k < 4; ++k)
    if (base + k < n) row[base + k] += add;
  if (b == 0 && threadIdx.x == 0) row[n] = total;
}

// fill all 4 CSRs (col only; low-VGPR, high-occupancy)
__global__ void k_fill_all(const int* p_src, const int* p_dst, const int* rowE_p, int* curE_p,
                           int* colE_p, int EP,
                           const int* d_src, const int* d_dst, const int* rowE_d, int* curE_d,
                           int* colE_d, int ED,
                           const int* p_sn, const int* p_si, const int* rowS_p, int* curS_p,
                           int* colS_p, int SP,
                           const int* d_sn, const int* d_si, const int* rowS_d, int* curS_d,
                           int* colS_d, int SD) {
  const int seg = blockIdx.x & 3;
  const int lb = blockIdx.x >> 2;
  const int stride = (gridDim.x >> 2) * blockDim.x;
  const int start = lb * blockDim.x + threadIdx.x;
  if (seg == 0) {
    for (int e = start; e < EP; e += stride) {
      const int d = p_dst[e];
      colE_p[rowE_p[d] + atomicAdd(&curE_p[d], 1)] = p_src[e];
    }
  } else if (seg == 1) {
    for (int e = start; e < ED; e += stride) {
      const int d = d_dst[e];
      colE_d[rowE_d[d] + atomicAdd(&curE_d[d], 1)] = d_src[e];
    }
  } else if (seg == 2) {
    for (int j = start; j < SP; j += stride) {
      const int t = p_si[j];
      colS_p[rowS_p[t] + atomicAdd(&curS_p[t], 1)] = p_sn[j];
    }
  } else {
    for (int j = start; j < SD; j += stride) {
      const int t = d_si[j];
      colS_d[rowS_d[t] + atomicAdd(&curS_d[t], 1)] = d_sn[j];
    }
  }
}

// ---------------- conv GEMM (split-bf16 MFMA, G out bf16, fused BN stats) ----------------
__global__ __launch_bounds__(256, 2)
void k_gemm_both(const unsigned short* Zhi0, const unsigned short* Zlo0,
                 const unsigned short* Whi0, const unsigned short* Wlo0,
                 unsigned short* G0, int nbk0,
                 const unsigned short* Zhi1, const unsigned short* Zlo1,
                 const unsigned short* Whi1, const unsigned short* Wlo1,
                 unsigned short* G1, float* stats_sl) {
  __shared__ unsigned short Bt[128 * 132];
  __shared__ float lstats[256];
  const int bid = blockIdx.x;
  const bool isP = bid >= nbk0;
  const int lb = isP ? bid - nbk0 : bid;
  const unsigned short* Zhi = isP ? Zhi1 : Zhi0;
  const unsigned short* Zlo = isP ? Zlo1 : Zlo0;
  const unsigned short* Wthi = isP ? Whi1 : Whi0;
  const unsigned short* Wtlo = isP ? Wlo1 : Wlo0;
  unsigned short* G = isP ? G1 : G0;
  const int slice = (isP ? 32 : 0) + (lb & 31);

  const int tid = threadIdx.x;
  const int w = tid >> 6;
  const int l = tid & 63;
  const int l15 = l & 15;
  const int kb = l >> 4;

  for (int i = tid; i < 128 * 16; i += 256) {
    const int c = i >> 4, k8 = i & 15;
    *(bf16x8*)(&Bt[c * 132 + k8 * 8]) = *(const bf16x8*)(Wthi + (size_t)c * 128 + k8 * 8);
  }
  lstats[tid] = 0.f;

  const int rbase = lb * 128 + w * 32 + l15;
  bf16x8 ahi[2][4], alo[2][4];
  #pragma unroll
  for (int rt = 0; rt < 2; ++rt)
    #pragma unroll
    for (int ks = 0; ks < 4; ++ks) {
      ahi[rt][ks] = *(const bf16x8*)(Zhi + (size_t)(rbase + rt * 16) * 128 + ks * 32 + kb * 8);
      alo[rt][ks] = *(const bf16x8*)(Zlo + (size_t)(rbase + rt * 16) * 128 + ks * 32 + kb * 8);
    }

  f32x4v acc[2][8];
  #pragma unroll
  for (int rt = 0; rt < 2; ++rt)
    #pragma unroll
    for (int ct = 0; ct < 8; ++ct)
      acc[rt][ct] = (f32x4v){0.f, 0.f, 0.f, 0.f};

  __syncthreads();
  #pragma unroll
  for (int ks = 0; ks < 4; ++ks) {
    #pragma unroll
    for (int ct = 0; ct < 8; ++ct) {
      const bf16x8 b = *(const bf16x8*)(&Bt[(ct * 16 + l15) * 132 + ks * 32 + kb * 8]);
      acc[0][ct] = __builtin_amdgcn_mfma_f32_16x16x32_bf16(ahi[0][ks], b, acc[0][ct], 0, 0, 0);
      acc[1][ct] = __builtin_amdgcn_mfma_f32_16x16x32_bf16(ahi[1][ks], b, acc[1][ct], 0, 0, 0);
      acc[0][ct] = __builtin_amdgcn_mfma_f32_16x16x32_bf16(alo[0][ks], b, acc[0][ct], 0, 0, 0);
      acc[1][ct] = __builtin_amdgcn_mfma_f32_16x16x32_bf16(alo[1][ks], b, acc[1][ct], 0, 0, 0);
    }
  }
  __syncthreads();

  for (int i = tid; i < 128 * 16; i += 256) {
    const int c = i >> 4, k8 = i & 15;
    *(bf16x8*)(&Bt[c * 132 + k8 * 8]) = *(const bf16x8*)(Wtlo + (size_t)c * 128 + k8 * 8);
  }
  __syncthreads();
  #pragma unroll
  for (int ks = 0; ks < 4; ++ks) {
    #pragma unroll
    for (int ct = 0; ct < 8; ++ct) {
      const bf16x8 b = *(const bf16x8*)(&Bt[(ct * 16 + l15) * 132 + ks * 32 + kb * 8]);
      acc[0][ct] = __builtin_amdgcn_mfma_f32_16x16x32_bf16(ahi[0][ks], b, acc[0][ct], 0, 0, 0);
      acc[1][ct] = __builtin_amdgcn_mfma_f32_16x16x32_bf16(ahi[1][ks], b, acc[1][ct], 0, 0, 0);
    }
  }

  float csum[8], csq[8];
  #pragma unroll
  for (int ct = 0; ct < 8; ++ct) { csum[ct] = 0.f; csq[ct] = 0.f; }
  #pragma unroll
  for (int rt = 0; rt < 2; ++rt) {
    const size_t grow = (size_t)lb * 128 + w * 32 + rt * 16 + (l >> 4) * 4;
    #pragma unroll
    for (int j = 0; j < 4; ++j) {
      unsigned short* gr = G + (grow + j) * 128 + l15;
      #pragma unroll
      for (int ct = 0; ct < 8; ++ct) {
        const float v = acc[rt][ct][j];
        gr[ct * 16] = f2b(v);
        csum[ct] += v;
        csq[ct] += v * v;
      }
    }
  }
  #pragma unroll
  for (int ct = 0; ct < 8; ++ct) {
    csum[ct] += __shfl_xor(csum[ct], 16);
    csum[ct] += __shfl_xor(csum[ct], 32);
    csq[ct] += __shfl_xor(csq[ct], 16);
    csq[ct] += __shfl_xor(csq[ct], 32);
  }
  if (l < 16) {
    #pragma unroll
    for (int ct = 0; ct < 8; ++ct) {
      atomicAdd(&lstats[ct * 16 + l], csum[ct]);
      atomicAdd(&lstats[128 + ct * 16 + l], csq[ct]);
    }
  }
  __syncthreads();
  atomicAdd(&stats_sl[(size_t)slice * 256 + tid], lstats[tid]);
}

// ---------------- encoder GEMM: fp32 X loaded directly, split in registers ----------------
__global__ __launch_bounds__(256, 2)
void k_gemm_enc_direct(const float* X0, int K0,
                       const unsigned short* Whi0, const unsigned short* Wlo0,
                       const float* bias0, unsigned short* G0, int nbk0,
                       const float* X1, int K1,
                       const unsigned short* Whi1, const unsigned short* Wlo1,
                       const float* bias1, unsigned short* G1) {
  __shared__ unsigned short Bt[128 * 132];
  const int bid = blockIdx.x;
  const bool isP = bid >= nbk0;
  const int lb = isP ? bid - nbk0 : bid;
  const float* X = isP ? X1 : X0;
  const int K = isP ? K1 : K0;
  const unsigned short* Wthi = isP ? Whi1 : Whi0;
  const unsigned short* Wtlo = isP ? Wlo1 : Wlo0;
  const float* bias = isP ? bias1 : bias0;
  unsigned short* G = isP ? G1 : G0;

  const int tid = threadIdx.x;
  const int w = tid >> 6;
  const int l = tid & 63;
  const int l15 = l & 15;
  const int kb = l >> 4;

  for (int i = tid; i < 128 * 16; i += 256) {
    const int c = i >> 4, k8 = i & 15;
    *(bf16x8*)(&Bt[c * 132 + k8 * 8]) = *(const bf16x8*)(Wthi + (size_t)c * 128 + k8 * 8);
  }

  const int rbase = lb * 128 + w * 32 + l15;
  bf16x8 ahi[2][4], alo[2][4];
  #pragma unroll
  for (int rt = 0; rt < 2; ++rt) {
    const float* xr = X + (size_t)(rbase + rt * 16) * K;
    #pragma unroll
    for (int ks = 0; ks < 4; ++ks) {
      #pragma unroll
      for (int j = 0; j < 8; ++j) {
        const int k = ks * 32 + kb * 8 + j;
        const float v = (k < K) ? xr[k] : 0.f;
        const unsigned short hi = f2b(v);
        ahi[rt][ks][j] = (short)hi;
        alo[rt][ks][j] = (short)f2b(v - b2f(hi));
      }
    }
  }

  f32x4v acc[2][8];
  #pragma unroll
  for (int rt = 0; rt < 2; ++rt)
    #pragma unroll
    for (int ct = 0; ct < 8; ++ct)
      acc[rt][ct] = (f32x4v){0.f, 0.f, 0.f, 0.f};

  __syncthreads();
  #pragma unroll
  for (int ks = 0; ks < 4; ++ks) {
    #pragma unroll
    for (int ct = 0; ct < 8; ++ct) {
      const bf16x8 b = *(const bf16x8*)(&Bt[(ct * 16 + l15) * 132 + ks * 32 + kb * 8]);
      acc[0][ct] = __builtin_amdgcn_mfma_f32_16x16x32_bf16(ahi[0][ks], b, acc[0][ct], 0, 0, 0);
      acc[1][ct] = __builtin_amdgcn_mfma_f32_16x16x32_bf16(ahi[1][ks], b, acc[1][ct], 0, 0, 0);
      acc[0][ct] = __builtin_amdgcn_mfma_f32_16x16x32_bf16(alo[0][ks], b, acc[0][ct], 0, 0, 0);
      acc[1][ct] = __builtin_amdgcn_mfma_f32_16x16x32_bf16(alo[1][ks], b, acc[1][ct], 0, 0, 0);
    }
  }
  __syncthreads();

  for (int i = tid; i < 128 * 16; i += 256) {
    const int c = i >> 4, k8 = i & 15;
    *(bf16x8*)(&Bt[c * 132 + k8 * 8]) = *(const bf16x8*)(Wtlo + (size_t)c * 128 + k8 * 8);
  }
  __syncthreads();
  #pragma unroll
  for (int ks = 0; ks < 4; ++ks) {
    #pragma unroll
    for (int ct = 0; ct < 8; ++ct) {
      const bf16x8 b = *(const bf16x8*)(&Bt[(ct * 16 + l15) * 132 + ks * 32 + kb * 8]);
      acc[0][ct] = __builtin_amdgcn_mfma_f32_16x16x32_bf16(ahi[0][ks], b, acc[0][ct], 0, 0, 0);
      acc[1][ct] = __builtin_amdgcn_mfma_f32_16x16x32_bf16(ahi[1][ks], b, acc[1][ct], 0, 0, 0);
    }
  }

  float bb[8];
  #pragma unroll
  for (int ct = 0; ct < 8; ++ct) bb[ct] = bias[ct * 16 + l15];
  #pragma unroll
  for (int rt = 0; rt < 2; ++rt) {
    const size_t grow = (size_t)lb * 128 + w * 32 + rt * 16 + (l >> 4) * 4;
    #pragma unroll
    for (int j = 0; j < 4; ++j) {
      unsigned short* gr = G + (grow + j) * 128 + l15;
      #pragma unroll
      for (int ct = 0; ct < 8; ++ct)
        gr[ct * 16] = f2b(acc[rt][ct][j] + bb[ct]);
    }
  }
}

// fold stat slices -> scale/shift; re-zeros slices; also zeroes sum_S for the coming sub pass
__global__ __launch_bounds__(128)
void k_bn_scale_both(float* __restrict__ stats_sl,
                     const float* g0, const float* b0, float invN0, float* scsh0, float* zero0,
                     const float* g1, const float* b1, float invN1, float* scsh1, float* zero1,
                     int zn4) {
  const int seg = blockIdx.x;
  float* base = stats_sl + (size_t)seg * 32 * 256;
  const float* g = seg ? g1 : g0;
  const float* bb = seg ? b1 : b0;
  const float invN = seg ? invN1 : invN0;
  float* scsh = seg ? scsh1 : scsh0;
  float* zero = seg ? zero1 : zero0;
  const int c = threadIdx.x;
  float s = 0.f, ss = 0.f;
  for (int k = 0; k < 32; ++k) {
    s += base[(size_t)k * 256 + c];
    ss += base[(size_t)k * 256 + 128 + c];
    base[(size_t)k * 256 + c] = 0.f;
    base[(size_t)k * 256 + 128 + c] = 0.f;
  }
  const float m = s * invN;
  const float var = ss * invN - m * m;
  const float sc = g[c] * rsqrtf(var + 1e-5f);
  scsh[c] = sc;
  scsh[HID + c] = bb[c] - m * sc;
  const float4 z = {0.f, 0.f, 0.f, 0.f};
  for (int i = c; i < zn4; i += 128) ((float4*)zero)[i] = z;
}

// fused upass+agg (G in bf16): Z_i = nrm_i^2*u(i) + sum_e nrm[col]*nrm_i*u(col)
template<bool HASF>
__global__ __launch_bounds__(256)
void k_agg_both(const int* rE0, const int* cE0, const unsigned short* G0,
                const float* scsh0, const int* bat0, const float* vx0, const float* nrm0,
                unsigned short* Zhi0, unsigned short* Zlo0, int nbk0,
                const int* rE1, const int* cE1, const unsigned short* G1,
                const float* scsh1, const int* bat1, const float* vx1, const float* nrm1,
                unsigned short* Zhi1, unsigned short* Zlo1) {
  const int bid = blockIdx.x;
  const bool isP = bid >= nbk0;
  const int lb = isP ? bid - nbk0 : bid;
  const int* rowp = isP ? rE1 : rE0;
  const int* colp = isP ? cE1 : cE0;
  const unsigned short* G = isP ? G1 : G0;
  const float* scsh = isP ? scsh1 : scsh0;
  const int* batch = isP ? bat1 : bat0;
  const float* vx = isP ? vx1 : vx0;
  const float* nrm = isP ? nrm1 : nrm0;
  unsigned short* Zhi = isP ? Zhi1 : Zhi0;
  unsigned short* Zlo = isP ? Zlo1 : Zlo0;

  const int tid = threadIdx.x;
  const int node = lb * 8 + (tid >> 5);
  const int c4 = tid & 31;
  float4 sc, shv;
  if constexpr (HASF) {
    sc = ((const float4*)scsh)[c4];
    shv = ((const float4*)(scsh + HID))[c4];
  }
  auto loadU = [&](int i) -> float4 {
    float4 v = b2f4(*(const ushort4*)(G + (size_t)i * HID + c4 * 4));
    if constexpr (HASF) {
      v.x = fmaxf(v.x * sc.x + shv.x, 0.f);
      v.y = fmaxf(v.y * sc.y + shv.y, 0.f);
      v.z = fmaxf(v.z * sc.z + shv.z, 0.f);
      v.w = fmaxf(v.w * sc.w + shv.w, 0.f);
    }
    const float4 u = *(const float4*)(vx + (size_t)batch[i] * HID + c4 * 4);
    v.x += u.x; v.y += u.y; v.z += u.z; v.w += u.w;
    return v;
  };
  const int lo = rowp[node], hi = rowp[node + 1];
  const float nv = nrm[node];
  const float s2 = nv * nv;
  float4 acc = loadU(node);
  acc.x *= s2; acc.y *= s2; acc.z *= s2; acc.w *= s2;
  int e = lo;
  for (; e + 4 <= hi; e += 4) {
    const int i0 = colp[e], i1 = colp[e + 1], i2 = colp[e + 2], i3 = colp[e + 3];
    const float w0 = nrm[i0] * nv, w1 = nrm[i1] * nv, w2 = nrm[i2] * nv, w3 = nrm[i3] * nv;
    const float4 v0 = loadU(i0);
    const float4 v1 = loadU(i1);
    const float4 v2 = loadU(i2);
    const float4 v3 = loadU(i3);
    acc.x += v0.x * w0 + v1.x * w1 + v2.x * w2 + v3.x * w3;
    acc.y += v0.y * w0 + v1.y * w1 + v2.y * w2 + v3.y * w3;
    acc.z += v0.z * w0 + v1.z * w1 + v2.z * w2 + v3.z * w3;
    acc.w += v0.w * w0 + v1.w * w1 + v2.w * w2 + v3.w * w3;
  }
  for (; e < hi; ++e) {
    const int i0 = colp[e];
    const float w = nrm[i0] * nv;
    const float4 v = loadU(i0);
    acc.x += v.x * w; acc.y += v.y * w; acc.z += v.z * w; acc.w += v.w * w;
  }
  ushort4 h, lo4;
  h.x = f2b(acc.x); lo4.x = f2b(acc.x - b2f(h.x));
  h.y = f2b(acc.y); lo4.y = f2b(acc.y - b2f(h.y));
  h.z = f2b(acc.z); lo4.z = f2b(acc.z - b2f(h.z));
  h.w = f2b(acc.w); lo4.w = f2b(acc.w - b2f(h.w));
  *(ushort4*)(Zhi + (size_t)node * HID + c4 * 4) = h;
  *(ushort4*)(Zlo + (size_t)node * HID + c4 * 4) = lo4;
}

// fused sub-gather + batch pooling (G in bf16)
__global__ __launch_bounds__(256)
void k_sub_pool_both(const int* rS0, const int* cS0, const unsigned short* G0, const float* scsh0,
                     const int* bat0, float* sumS0, int nbk0,
                     const int* rS1, const int* cS1, const unsigned short* G1, const float* scsh1,
                     const int* bat1, float* sumS1) {
  __shared__ float sh[8][HID];
  __shared__ int batl[8];
  const int bid = blockIdx.x;
  const bool isP = bid >= nbk0;
  const int lb = isP ? bid - nbk0 : bid;
  const int* rowp = isP ? rS1 : rS0;
  const int* colp = isP ? cS1 : cS0;
  const unsigned short* G = isP ? G1 : G0;
  const float* scsh = isP ? scsh1 : scsh0;
  const int* batch = isP ? bat1 : bat0;
  float* sumS = isP ? sumS1 : sumS0;

  const int tid = threadIdx.x;
  const int grp = tid >> 5;
  const int node = lb * 8 + grp;
  const int c4 = tid & 31;
  const float4 sc = ((const float4*)scsh)[c4];
  const float4 shv = ((const float4*)(scsh + HID))[c4];
  const int lo = rowp[node], hi = rowp[node + 1];
  float4 acc = {0.f, 0.f, 0.f, 0.f};
  int e = lo;
  for (; e + 4 <= hi; e += 4) {
    const int i0 = colp[e], i1 = colp[e + 1], i2 = colp[e + 2], i3 = colp[e + 3];
    const float4 v0 = b2f4(*(const ushort4*)(G + (size_t)i0 * HID + c4 * 4));
    const float4 v1 = b2f4(*(const ushort4*)(G + (size_t)i1 * HID + c4 * 4));
    const float4 v2 = b2f4(*(const ushort4*)(G + (size_t)i2 * HID + c4 * 4));
    const float4 v3 = b2f4(*(const ushort4*)(G + (size_t)i3 * HID + c4 * 4));
    acc.x += fmaxf(v0.x * sc.x + shv.x, 0.f) + fmaxf(v1.x * sc.x + shv.x, 0.f)
           + fmaxf(v2.x * sc.x + shv.x, 0.f) + fmaxf(v3.x * sc.x + shv.x, 0.f);
    acc.y += fmaxf(v0.y * sc.y + shv.y, 0.f) + fmaxf(v1.y * sc.y + shv.y, 0.f)
           + fmaxf(v2.y * sc.y + shv.y, 0.f) + fmaxf(v3.y * sc.y + shv.y, 0.f);
    acc.z += fmaxf(v0.z * sc.z + shv.z, 0.f) + fmaxf(v1.z * sc.z + shv.z, 0.f)
           + fmaxf(v2.z * sc.z + shv.z, 0.f) + fmaxf(v3.z * sc.z + shv.z, 0.f);
    acc.w += fmaxf(v0.w * sc.w + shv.w, 0.f) + fmaxf(v1.w * sc.w + shv.w, 0.f)
           + fmaxf(v2.w * sc.w + shv.w, 0.f) + fmaxf(v3.w * sc.w + shv.w, 0.f);
  }
  for (; e < hi; ++e) {
    const float4 v = b2f4(*(const ushort4*)(G + (size_t)colp[e] * HID + c4 * 4));
    acc.x += fmaxf(v.x * sc.x + shv.x, 0.f);
    acc.y += fmaxf(v.y * sc.y + shv.y, 0.f);
    acc.z += fmaxf(v.z * sc.z + shv.z, 0.f);
    acc.w += fmaxf(v.w * sc.w + shv.w, 0.f);
  }
  const float inv = 1.0f / fmaxf((float)(hi - lo), 1.0f);
  acc.x *= inv; acc.y *= inv; acc.z *= inv; acc.w *= inv;
  ((float4*)&sh[grp][0])[c4] = acc;
  if (tid < 8) batl[tid] = batch[lb * 8 + tid];
  __syncthreads();
  if (tid < HID) {
    int cur = batl[0];
    float a = 0.f;
    #pragma unroll
    for (int g = 0; g < 8; ++g) {
      if (batl[g] != cur) {
        atomicAdd(&sumS[(size_t)cur * HID + tid], a);
        a = 0.f;
        cur = batl[g];
      }
      a += sh[g][tid];
    }
    atomicAdd(&sumS[(size_t)cur * HID + tid], a);
  }
}

// vn update for both graphs (grid 2B)
__global__ __launch_bounds__(128)
void k_vn_update_both(const float* ps0, float* vx0, const float* W0, const float* b0,
                      const float* ps1, float* vx1, const float* W1, const float* b1, int B) {
  const int gb = blockIdx.x;
  const bool isP = gb >= B;
  const int b = isP ? gb - B : gb;
  const float* pooledSum = isP ? ps1 : ps0;
  float* vx = isP ? vx1 : vx0;
  const float* W = isP ? W1 : W0;
  const float* bias = isP ? b1 : b0;
  const int c = threadIdx.x;
  __shared__ float xin[HID];
  xin[c] = pooledSum[(size_t)b * HID + c] + vx[(size_t)b * HID + c];
  __syncthreads();
  float acc = bias[c];
  #pragma unroll 8
  for (int k = 0; k < HID; k += 4) {
    const float4 x = *(const float4*)&xin[k];
    acc += x.x * W[k * HID + c] + x.y * W[(k + 1) * HID + c]
         + x.z * W[(k + 2) * HID + c] + x.w * W[(k + 3) * HID + c];
  }
  vx[(size_t)b * HID + c] += fmaxf(acc, 0.0f);
}

// final MLP with inline cross-modal A computation
__global__ __launch_bounds__(128)
void k_final_mlp_both(const float* sum_Sd, const float* sum_Sp,
                      const float* nb_d, const float* nb_p,
                      const float* f0, const float* W0, const float* b0,
                      const float* f1, const float* W1, const float* b1,
                      float* __restrict__ fpre, int B) {
  const int gb = blockIdx.x;
  const bool isP = gb >= B;
  const int b = isP ? gb - B : gb;
  const float* feat = isP ? f1 : f0;
  const float* W = isP ? W1 : W0;
  const float* bias = isP ? b1 : b0;
  const int c = threadIdx.x;
  __shared__ float xin[2 * HID];
  const float nd = nb_d[b], np_ = nb_p[b];
  const float md = sum_Sd[(size_t)b * HID + c] / fmaxf(nd, 1.f);
  const float mp = sum_Sp[(size_t)b * HID + c] / fmaxf(np_, 1.f);
  xin[c] = isP ? (mp + (np_ > 0.f ? md : 0.f)) : (md + (nd > 0.f ? mp : 0.f));
  xin[HID + c] = feat[(size_t)b * HID + c];
  __syncthreads();
  float acc = bias[c];
  #pragma unroll 8
  for (int k = 0; k < 2 * HID; k += 4) {
    const float4 x = *(const float4*)&xin[k];
    acc += x.x * W[k * HID + c] + x.y * W[(k + 1) * HID + c]
         + x.z * W[(k + 2) * HID + c] + x.w * W[(k + 3) * HID + c];
  }
  fpre[(size_t)gb * HID + c] = acc;
}

__global__ __launch_bounds__(256)
void k_bn_stats_both(const float* __restrict__ fpre, float* __restrict__ statsF, int B) {
  __shared__ float sh[2][256];
  const int seg = blockIdx.x >= 128 ? 1 : 0;
  const int lb = blockIdx.x - seg * 128;
  const float* X = fpre + (size_t)seg * B * HID;
  float* stats = statsF + seg * 256;
  const int tid = threadIdx.x;
  const int c = tid & (HID - 1);
  const int half = tid >> 7;
  float s = 0.f, ss = 0.f;
  for (int r = lb * 2 + half; r < B; r += 256) {
    const float v = X[(size_t)r * HID + c];
    s += v; ss += v * v;
  }
  sh[0][tid] = s; sh[1][tid] = ss;
  __syncthreads();
  if (tid < HID) {
    atomicAdd(&stats[c], sh[0][tid] + sh[0][tid + 128]);
    atomicAdd(&stats[HID + c], sh[1][tid] + sh[1][tid + 128]);
  }
}

__global__ void k_bn_apply_both(const float* __restrict__ fpre, float* __restrict__ out,
                                const float* __restrict__ statsF,
                                const float* g0, const float* b0,
                                const float* g1, const float* b1, int B, float invN) {
  const int stride = gridDim.x * blockDim.x;
  const int n4 = 2 * B * 32;
  for (int i = blockIdx.x * blockDim.x + threadIdx.x; i < n4; i += stride) {
    const int seg = i >= B * 32 ? 1 : 0;
    const int c4 = i & 31;
    const float* stats = statsF + seg * 256;
    const float4 m4 = ((const float4*)stats)[c4];
    const float4 q4 = ((const float4*)stats)[32 + c4];
    const float4 g4 = ((const float4*)(seg ? g1 : g0))[c4];
    const float4 b4 = ((const float4*)(seg ? b1 : b0))[c4];
    float4 v = ((const float4*)fpre)[i];
    float m, va;
    m = m4.x * invN; va = q4.x * invN - m * m; v.x = (v.x - m) * rsqrtf(va + 1e-5f) * g4.x + b4.x;
    m = m4.y * invN; va = q4.y * invN - m * m; v.y = (v.y - m) * rsqrtf(va + 1e-5f) * g4.y + b4.y;
    m = m4.z * invN; va = q4.z * invN - m * m; v.z = (v.z - m) * rsqrtf(va + 1e-5f) * g4.z + b4.z;
    m = m4.w * invN; va = q4.w * invN - m * m; v.w = (v.w - m) * rsqrtf(va + 1e-5f) * g4.w + b4.w;
    ((float4*)out)[i] = v;
  }
}

// ---------------- host launch ----------------
extern "C" void kernel_launch(void* const* d_in, const int* in_sizes, int n_in,
                              void* d_out, int out_size, void* d_ws, size_t ws_size,
                              hipStream_t stream) {
  const float* drug_x   = (const float*)d_in[0];
  const float* prot_x   = (const float*)d_in[1];
  const float* d_feat   = (const float*)d_in[2];
  const float* p_feat   = (const float*)d_in[3];
  const int*   d_ei     = (const int*)d_in[4];
  const int*   d_batch  = (const int*)d_in[5];
  const int*   d_sn     = (const int*)d_in[6];
  const int*   d_si     = (const int*)d_in[7];
  const int*   p_ei     = (const int*)d_in[8];
  const int*   p_batch  = (const int*)d_in[9];
  const int*   p_sn     = (const int*)d_in[10];
  const int*   p_si     = (const int*)d_in[11];
  const float* enc_Wd   = (const float*)d_in[12];
  const float* enc_bd   = (const float*)d_in[13];
  const float* enc_Wp   = (const float*)d_in[14];
  const float* enc_bp   = (const float*)d_in[15];
  const float* convW_d  = (const float*)d_in[16];
  const float* convW_p  = (const float*)d_in[18];
  const float* bng_d    = (const float*)d_in[20];
  const float* bnb_d    = (const float*)d_in[21];
  const float* bng_p    = (const float*)d_in[22];
  const float* bnb_p    = (const float*)d_in[23];
  const float* vn_emb_d = (const float*)d_in[24];
  const float* vn_emb_p = (const float*)d_in[25];
  const float* vnW_d    = (const float*)d_in[26];
  const float* vnb_d    = (const float*)d_in[27];
  const float* vnW_p    = (const float*)d_in[28];
  const float* vnb_p    = (const float*)d_in[29];
  const float* mlpd1_W  = (const float*)d_in[30];
  const float* mlpd1_b  = (const float*)d_in[31];
  const float* mlpd1_g  = (const float*)d_in[32];
  const float* mlpd1_be = (const float*)d_in[33];
  const float* mlpp1_W  = (const float*)d_in[34];
  const float* mlpp1_b  = (const float*)d_in[35];
  const float* mlpp1_g  = (const float*)d_in[36];
  const float* mlpp1_be = (const float*)d_in[37];

  const int ND = in_sizes[5];
  const int ED = in_sizes[4] / 2;
  const int SD = in_sizes[6];
  const int NP = in_sizes[9];
  const int EP = in_sizes[8] / 2;
  const int SP = in_sizes[10];
  const int B  = in_sizes[2] / HID;
  (void)n_in; (void)out_size; (void)ws_size;

  char* wsb = (char*)d_ws;
  size_t off = 0;
  auto alloc = [&](size_t bytes) -> void* {
    void* p = (void*)(wsb + off);
    off = (off + bytes + 255) & ~(size_t)255;
    return p;
  };
  // node buffers (G and Z bf16)
  unsigned short* Gp = (unsigned short*)alloc((size_t)NP * HID * 2);
  unsigned short* Zhi_p = (unsigned short*)alloc((size_t)NP * HID * 2);
  unsigned short* Zlo_p = (unsigned short*)alloc((size_t)NP * HID * 2);
  unsigned short* Gd = (unsigned short*)alloc((size_t)ND * HID * 2);
  unsigned short* Zhi_d = (unsigned short*)alloc((size_t)ND * HID * 2);
  unsigned short* Zlo_d = (unsigned short*)alloc((size_t)ND * HID * 2);
  unsigned short* WhiAll = (unsigned short*)alloc((size_t)8 * HID * HID * 2);
  unsigned short* WloAll = (unsigned short*)alloc((size_t)8 * HID * HID * 2);
  // CSR
  float* nrm_p = (float*)alloc((size_t)NP * 4);
  float* nrm_d = (float*)alloc((size_t)ND * 4);
  int* rowE_p = (int*)alloc((size_t)(NP + 1) * 4);
  int* rowE_d = (int*)alloc((size_t)(ND + 1) * 4);
  int* rowS_p = (int*)alloc((size_t)(NP + 1) * 4);
  int* rowS_d = (int*)alloc((size_t)(ND + 1) * 4);
  int* colE_p = (int*)alloc((size_t)EP * 4);
  int* colE_d = (int*)alloc((size_t)ED * 4);
  int* colS_p = (int*)alloc((size_t)SP * 4);
  int* colS_d = (int*)alloc((size_t)SD * 4);
  int* aux    = (int*)alloc(4 * 256 * 4);
  float* vx_d  = (float*)alloc((size_t)B * HID * 4);
  float* vx_p  = (float*)alloc((size_t)B * HID * 4);
  float* sum_Sd = (float*)alloc((size_t)B * HID * 4);
  float* sum_Sp = (float*)alloc((size_t)B * HID * 4);
  float* nb_d  = (float*)alloc((size_t)B * 4);
  float* nb_p  = (float*)alloc((size_t)B * 4);
  float* scsh_d = (float*)alloc(2 * HID * 4);
  float* scsh_p = (float*)alloc(2 * HID * 4);
  float* fpre  = (float*)alloc((size_t)2 * B * HID * 4);
  float* statsF = (float*)alloc(2 * 256 * 4);
  // zero region
  const size_t zstart = off;
  int* deg_p  = (int*)alloc((size_t)NP * 4);
  int* deg_d  = (int*)alloc((size_t)ND * 4);
  int* scnt_p = (int*)alloc((size_t)NP * 4);
  int* scnt_d = (int*)alloc((size_t)ND * 4);
  int* curE_p = (int*)alloc((size_t)NP * 4);
  int* curE_d = (int*)alloc((size_t)ND * 4);
  int* curS_p = (int*)alloc((size_t)NP * 4);
  int* curS_d = (int*)alloc((size_t)ND * 4);
  float* stats_sl = (float*)alloc((size_t)64 * 256 * 4);
  const size_t zend = off;

  const int* d_src = d_ei;  const int* d_dst = d_ei + ED;
  const int* p_src = p_ei;  const int* p_dst = p_ei + EP;

  // ---- memset + merged prep ----
  hipMemsetAsync(wsb + zstart, 0, zend - zstart, stream);
  k_prep1<<<4 * HB + 256 + 128, 256, 0, stream>>>(
      p_dst, EP, deg_p, d_dst, ED, deg_d, p_si, SP, scnt_p, d_si, SD, scnt_d,
      convW_d, convW_p, enc_Wd, enc_Wp, WhiAll, WloAll,
      vn_emb_d, d_feat, vx_d, vn_emb_p, p_feat, vx_p, B * HID);
  k_nrm_nb<<<1024, 256, 0, stream>>>(deg_d, nrm_d, ND, deg_p, nrm_p, NP,
                                     d_batch, nb_d, p_batch, nb_p, B);
  const int nbP = (NP + 1023) / 1024, nbD = (ND + 1023) / 1024;
  k_scan1_all<<<2 * nbP + 2 * nbD, 256, 0, stream>>>(
      deg_p, rowE_p, NP, nbP, deg_d, rowE_d, ND, nbD,
      scnt_p, rowS_p, NP, nbP, scnt_d, rowS_d, ND, nbD, aux);
  k_scan2_all<<<4, 256, 0, stream>>>(aux, nbP, nbD, nbP, nbD);
  k_scan3_all<<<2 * nbP + 2 * nbD, 256, 0, stream>>>(
      rowE_p, NP, nbP, EP, rowE_d, ND, nbD, ED,
      rowS_p, NP, nbP, SP, rowS_d, ND, nbD, SD, aux);
  k_fill_all<<<4096, 256, 0, stream>>>(
      p_src, p_dst, rowE_p, curE_p, colE_p, EP,
      d_src, d_dst, rowE_d, curE_d, colE_d, ED,
      p_sn, p_si, rowS_p, curS_p, colS_p, SP,
      d_sn, d_si, rowS_d, curS_d, colS_d, SD);

  // ---- encoder GEMM with in-register fp32->split-bf16 conversion ----
  k_gemm_enc_direct<<<ND / 128 + NP / 128, 256, 0, stream>>>(
      drug_x, 78, WhiAll + (size_t)6 * HID * HID, WloAll + (size_t)6 * HID * HID,
      enc_bd, Gd, ND / 128,
      prot_x, 70, WhiAll + (size_t)7 * HID * HID, WloAll + (size_t)7 * HID * HID,
      enc_bp, Gp);

  for (int l = 0; l < 3; ++l) {
    if (l == 0)
      k_agg_both<false><<<ND / 8 + NP / 8, 256, 0, stream>>>(
          rowE_d, colE_d, Gd, nullptr, d_batch, vx_d, nrm_d, Zhi_d, Zlo_d, ND / 8,
          rowE_p, colE_p, Gp, nullptr, p_batch, vx_p, nrm_p, Zhi_p, Zlo_p);
    else
      k_agg_both<true><<<ND / 8 + NP / 8, 256, 0, stream>>>(
          rowE_d, colE_d, Gd, scsh_d, d_batch, vx_d, nrm_d, Zhi_d, Zlo_d, ND / 8,
          rowE_p, colE_p, Gp, scsh_p, p_batch, vx_p, nrm_p, Zhi_p, Zlo_p);
    k_gemm_both<<<ND / 128 + NP / 128, 256, 0, stream>>>(
        Zhi_d, Zlo_d, WhiAll + (size_t)l * HID * HID, WloAll + (size_t)l * HID * HID,
        Gd, ND / 128,
        Zhi_p, Zlo_p, WhiAll + (size_t)(3 + l) * HID * HID, WloAll + (size_t)(3 + l) * HID * HID,
        Gp, stats_sl);
    k_bn_scale_both<<<2, 128, 0, stream>>>(stats_sl,
        bng_d + l * HID, bnb_d + l * HID, 1.0f / (float)ND, scsh_d, sum_Sd,
        bng_p + l * HID, bnb_p + l * HID, 1.0f / (float)NP, scsh_p, sum_Sp,
        B * HID / 4);
    k_sub_pool_both<<<ND / 8 + NP / 8, 256, 0, stream>>>(
        rowS_d, colS_d, Gd, scsh_d, d_batch, sum_Sd, ND / 8,
        rowS_p, colS_p, Gp, scsh_p, p_batch, sum_Sp);
    if (l < 2)
      k_vn_update_both<<<2 * B, 128, 0, stream>>>(
          sum_Sd, vx_d, vnW_d + (size_t)l * HID * HID, vnb_d + l * HID,
          sum_Sp, vx_p, vnW_p + (size_t)l * HID * HID, vnb_p + l * HID, B);
  }

  // ---- final ----
  k_final_mlp_both<<<2 * B, 128, 0, stream>>>(sum_Sd, sum_Sp, nb_d, nb_p,
                                              d_feat, mlpd1_W, mlpd1_b,
                                              p_feat, mlpp1_W, mlpp1_b, fpre, B);
  hipMemsetAsync(statsF, 0, 2 * 256 * 4, stream);
  k_bn_stats_both<<<256, 256, 0, stream>>>(fpre, statsF, B);
  k_bn_apply_both<<<128, 256, 0, stream>>>(fpre, (float*)d_out, statsF,
                                           mlpd1_g, mlpd1_be, mlpp1_g, mlpp1_be,
                                           B, 1.0f / (float)B);
}